// Round 8
// baseline (209.677 us; speedup 1.0000x reference)
//
#include <hip/hip_runtime.h>
#include <stdint.h>

typedef __bf16 bf16x8 __attribute__((ext_vector_type(8)));
typedef float  f32x4  __attribute__((ext_vector_type(4)));

static constexpr int Bn = 32, Cn = 128, Hn = 64, Wn = 64, HWn = 4096;
static constexpr size_t OFF_XT    = 0;                       // 33,554,432 B (bf16 x, [b][pix][128ci] records)
static constexpr size_t OFF_WF    = 33554432;                // 221,184 B (B-fragment-ordered weights)
static constexpr size_t OFF_IDX   = 33775616;                // 1,536 B
static constexpr size_t OFF_M     = 33777152;                // 33,554,432 B (median result, bf16, NCHW)
static constexpr size_t OFF_STATS = 67331584;                // 32,768 B (32 shadow copies of [256] stats)
static constexpr size_t OFF_ZERO  = 67364352;                // 256 B zero page (halo OOB source)

__device__ __forceinline__ unsigned short f32_to_bf16(float f) {
    union { float f; unsigned u; } v; v.f = f;
    unsigned u = v.u;
    return (unsigned short)((u + 0x7FFFu + ((u >> 16) & 1u)) >> 16);
}
__device__ __forceinline__ float bf16_to_f32(unsigned short h) {
    union { unsigned u; float f; } v; v.u = ((unsigned)h) << 16;
    return v.f;
}
__device__ __forceinline__ float bf_lo(unsigned w) {
    union { unsigned u; float f; } v; v.u = w << 16; return v.f;
}
__device__ __forceinline__ float bf_hi(unsigned w) {
    union { unsigned u; float f; } v; v.u = w & 0xffff0000u; return v.f;
}
__device__ __forceinline__ float med3(float z0, float z1, float z2) {
    float lo = fminf(z0, z1), hi = fmaxf(z0, z1);
    return fmaxf(lo, fminf(hi, z2));
}
// direct global->LDS DMA, 16 B per lane (dest = wave-uniform base, HW adds lane*16)
__device__ __forceinline__ void gload_lds16(const unsigned short* g, unsigned short* l) {
    __builtin_amdgcn_global_load_lds(
        (const __attribute__((address_space(1))) unsigned int*)(const void*)g,
        (__attribute__((address_space(3))) unsigned int*)(void*)l,
        16, 0, 0);
}

// ---- K_prep: wsk (blocks 0..431) + idx/zero (432) + transpose (433..2480) ----
__global__ __launch_bounds__(256) void k_prep(const float* __restrict__ x,
                                              unsigned short* __restrict__ xT,
                                              const float* __restrict__ w2,
                                              const float* __restrict__ hs,
                                              const float* __restrict__ ss,
                                              unsigned short* __restrict__ wf,
                                              int* __restrict__ idx,
                                              float* __restrict__ stats32,
                                              float* __restrict__ zerop) {
    __shared__ __align__(16) unsigned char smraw[20480];
    int t = threadIdx.x;
    if (blockIdx.x < 432) {
        // sketched weights: per-block LDS idx table, then LDS-scan + sparse w2 gather.
        int*   idxs = (int*)smraw;
        float* sss  = (float*)(smraw + 1536);
        for (int i = t; i < 384; i += 256) {
            int j = i >> 7, c = i & 127;
            int found = 0;
#pragma unroll
            for (int d = 0; d < 32; ++d)
                if (hs[(j * 32 + d) * 128 + c] > 0.5f) found = d;
            idxs[i] = found;
            sss[i]  = ss[i];
        }
        __syncthreads();
        int f = blockIdx.x * 256 + t;   // 110592 total
        int jj   = f & 7;
        int lane = (f >> 3) & 63;
        int nt   = (f >> 9) % 6;
        int qt   = f / (512 * 6);
        int tp   = qt % 9;
        int q    = qt / 9;
        int k  = ((lane >> 4) << 3) + jj;
        int ci = q * 32 + k;
        int n  = nt * 16 + (lane & 15);
        int j = n >> 5, d = n & 31;
        const int*   ij = idxs + j * 128;
        const float* sj = sss  + j * 128;
        float sum = 0.f;
        for (int c = 0; c < 128; ++c)
            if (ij[c] == d) sum += sj[c] * w2[(c * 128 + ci) * 9 + tp];
        wf[f] = f32_to_bf16(sum);
    } else if (blockIdx.x == 432) {
        // recover idx from one-hot hs + zero shadow stats + zero page
        for (int i = t; i < 384; i += 256) {
            int j = i >> 7, c = i & 127;
            int found = 0;
            for (int d = 0; d < 32; ++d)
                if (hs[(j * 32 + d) * 128 + c] > 0.5f) found = d;
            idx[i] = found;
        }
        for (int i = t; i < 8192; i += 256) stats32[i] = 0.f;
        if (t < 64) zerop[t] = 0.f;
    } else {
        // x NCHW fp32 -> xT[b][pix][128ci] bf16; this block writes ci chunk q (64 B
        // piece at byte offset q*64 of each 256 B pixel record).
        unsigned short* sm = (unsigned short*)smraw;   // 256*40 ushorts = 20480 B
        int blk = blockIdx.x - 433;           // b*64 + q*16 + pt
        int pt = blk & 15, q = (blk >> 4) & 3, b = blk >> 6;
        int p0 = pt * 256;
        const float* xp = x + ((size_t)(b * Cn + q * 32) * HWn) + p0 + t;
#pragma unroll
        for (int cil = 0; cil < 32; ++cil)
            sm[t * 40 + cil] = f32_to_bf16(xp[(size_t)cil * HWn]);
        __syncthreads();
        uint4* dst = (uint4*)xT;
#pragma unroll
        for (int pass = 0; pass < 4; ++pass) {
            int pix = pass * 64 + (t >> 2);
            int ch  = t & 3;
            dst[(size_t)(b * HWn + p0 + pix) * 16 + q * 4 + ch] = *(const uint4*)(&sm[pix * 40 + ch * 8]);
        }
    }
}

// ---- K2: conv(96ch) + unsketch + median3 + fused BN stats -> m (bf16, NCHW) ----
// grid 1024 = b*32 + tile; tile = 2 rows x 64 cols (128 px).
// 4 waves: wv = (row_l<<1)|nh -> wave owns output row row_l, N-half nh; acc[4][3].
// ONE stage per block: full-ci halo (4 rows x 66 px x 256 B = 67,584 B) via
// global_load_lds, ONE barrier, then 36 taps / 432 MFMAs per wave of pure
// LDS+MFMA + L2-hot bfr loads — no staging, no barriers, no vmcnt events in the
// whole compute loop (kills the per-q stage/drain convoy all prior variants shared).
// Swizzle pair (rule #21): LDS holds global slot cl^(r&7) at dest slot cl
// (inverse-swizzled DMA source); afr reads slot (4q+quad)^(r&7) -> 2-way banks.
__global__ __launch_bounds__(256, 2) void k_conv(const unsigned short* __restrict__ xT,
                                                 const unsigned short* __restrict__ wf,
                                                 const int* __restrict__ idx,
                                                 const float* __restrict__ ss,
                                                 unsigned short* __restrict__ m_out,
                                                 float* __restrict__ stats32,
                                                 const unsigned short* __restrict__ zerop) {
    // halo: 264 records x 256 B = 67,584 B; epilogue y [96][136] = 52,224 B aliases it
    __shared__ __align__(16) unsigned short sm[33792];
    int tid  = threadIdx.x;
    int blk  = blockIdx.x;
    int tile = blk & 31, b = blk >> 5;
    int ty0  = tile * 2;
    int wv   = tid >> 6, lane = tid & 63;
    int quad = lane >> 4, l15 = lane & 15;
    int row_l = wv >> 1, nh = wv & 1;

    // ---- single stage: 4224 chunks of 16 B ----
    {
        const unsigned short* xb = xT + (size_t)b * (HWn * 128);
#pragma unroll
        for (int i = 0; i < 17; ++i) {
            if (i < 16 || tid < 128) {
                int k  = i * 256 + tid;
                int r  = k >> 4, cl = k & 15;
                int sl = cl ^ (r & 7);                 // inverse read-swizzle on source
                int hy = r / 66, hx = r - hy * 66;
                int gy = ty0 + hy - 1, gx = hx - 1;
                const unsigned short* src = (gy >= 0 && gy < 64 && gx >= 0 && gx < 64)
                        ? (xb + ((size_t)(gy * 64 + gx) * 128 + sl * 8)) : zerop;
                gload_lds16(src, &sm[(size_t)k * 8]);
            }
        }
    }
    __syncthreads();   // drains DMAs (compiler emits vmcnt(0) before barrier)

    f32x4 acc[4][3];
#pragma unroll
    for (int a = 0; a < 4; ++a)
#pragma unroll
        for (int nb = 0; nb < 3; ++nb) acc[a][nb] = (f32x4){0.f, 0.f, 0.f, 0.f};

    const unsigned short* wl = wf + (size_t)(nh * 3) * 512 + lane * 8;

    for (int q = 0; q < 4; ++q) {
#pragma unroll
        for (int tp = 0; tp < 9; ++tp) {
            int dy = tp / 3, dx = tp % 3;
            bf16x8 bfr[3];
            const unsigned short* wb = wl + (size_t)((q * 9 + tp) * 6) * 512;
#pragma unroll
            for (int nb = 0; nb < 3; ++nb)
                bfr[nb] = *(const bf16x8*)(wb + nb * 512);
            int rb = (row_l + dy) * 66 + l15 + dx;     // halo pixel of mq=0
            int sw = ((4 * q + quad) ^ (rb & 7)) * 16; // swizzled slot byte (rb&7 inv. in mq)
            bf16x8 afr[4];
#pragma unroll
            for (int mq = 0; mq < 4; ++mq)
                afr[mq] = *(const bf16x8*)((const unsigned char*)sm + (rb + mq * 16) * 256 + sw);
            __builtin_amdgcn_s_setprio(1);
#pragma unroll
            for (int mq = 0; mq < 4; ++mq)
#pragma unroll
                for (int nb = 0; nb < 3; ++nb)
                    acc[mq][nb] = __builtin_amdgcn_mfma_f32_16x16x32_bf16(afr[mq], bfr[nb], acc[mq][nb], 0, 0, 0);
            __builtin_amdgcn_s_setprio(0);
        }
    }

    __syncthreads();   // all waves done reading halo before the y-tile alias
    // y-dump: channel-major [96][136] (272 B stride: 16 B-aligned rows, 4-bank skew)
#pragma unroll
    for (int mq = 0; mq < 4; ++mq)
#pragma unroll
        for (int nb = 0; nb < 3; ++nb) {
            int ch = nh * 48 + nb * 16 + l15;
            int px = row_l * 64 + mq * 16 + quad * 4;
            ushort4 v;
            v.x = f32_to_bf16(acc[mq][nb][0]);
            v.y = f32_to_bf16(acc[mq][nb][1]);
            v.z = f32_to_bf16(acc[mq][nb][2]);
            v.w = f32_to_bf16(acc[mq][nb][3]);
            *(ushort4*)(&sm[ch * 136 + px]) = v;
        }
    __syncthreads();
    // median-of-3: 16 lanes per channel (8 px per b128 read), 4 channels/wave/iter
    unsigned short* mpb = m_out + (size_t)b * Cn * HWn + tile * 128 + l15 * 8;
    float* stp = stats32 + (blk & 31) * 256;
#pragma unroll 2
    for (int i = 0; i < 8; ++i) {
        int c = wv * 32 + i * 4 + quad;
        int r0 = idx[c], r1 = 32 + idx[128 + c], r2 = 64 + idx[256 + c];
        float sg0 = ss[c], sg1 = ss[128 + c], sg2 = ss[256 + c];
        uint4 w0 = *(const uint4*)(&sm[r0 * 136 + l15 * 8]);
        uint4 w1 = *(const uint4*)(&sm[r1 * 136 + l15 * 8]);
        uint4 w2v = *(const uint4*)(&sm[r2 * 136 + l15 * 8]);
        const unsigned* u0 = (const unsigned*)&w0;
        const unsigned* u1 = (const unsigned*)&w1;
        const unsigned* u2 = (const unsigned*)&w2v;
        uint4 R;
        unsigned* rw = (unsigned*)&R;
        float s = 0.f, s2 = 0.f;
#pragma unroll
        for (int e = 0; e < 4; ++e) {
            float mlo = med3(sg0 * bf_lo(u0[e]), sg1 * bf_lo(u1[e]), sg2 * bf_lo(u2[e]));
            float mhi = med3(sg0 * bf_hi(u0[e]), sg1 * bf_hi(u1[e]), sg2 * bf_hi(u2[e]));
            s  += mlo + mhi;
            s2 += mlo * mlo + mhi * mhi;
            rw[e] = (unsigned)f32_to_bf16(mlo) | ((unsigned)f32_to_bf16(mhi) << 16);
        }
        *(uint4*)(mpb + (size_t)c * HWn) = R;
#pragma unroll
        for (int o = 8; o > 0; o >>= 1) { s += __shfl_xor(s, o); s2 += __shfl_xor(s2, o); }
        if (l15 == 0) { atomicAdd(&stp[c], s); atomicAdd(&stp[128 + c], s2); }
    }
}

// ---- K3: out = relu(m*sc+sh) + x; BN coefficients reduced once per block ----
__global__ __launch_bounds__(256) void k_apply(const unsigned short* __restrict__ m,
                                               const float* __restrict__ x,
                                               const float* __restrict__ stats32,
                                               const float* __restrict__ gamma,
                                               const float* __restrict__ beta,
                                               float* __restrict__ out) {
    __shared__ float co[2];
    int tid = threadIdx.x;
    int i4 = blockIdx.x * 256 + tid;              // 4,194,304 groups of 4
    int c = (blockIdx.x >> 2) & 127;              // block-uniform channel
    if (tid < 64) {
        float v = stats32[(tid & 31) * 256 + ((tid >> 5) << 7) + c];
#pragma unroll
        for (int o = 16; o > 0; o >>= 1) v += __shfl_xor(v, o);
        if ((tid & 31) == 0) co[tid >> 5] = v;
    }
    __syncthreads();
    const float N = 131072.f;
    float mean = co[0] / N;
    float var  = co[1] / N - mean * mean;
    float sc   = gamma[c] * rsqrtf(var + 1e-5f);
    float sh   = beta[c] - mean * sc;
    ushort4 mv = ((const ushort4*)m)[i4];
    float4  xv = ((const float4*)x)[i4];
    float4 o;
    o.x = fmaxf(bf16_to_f32(mv.x) * sc + sh, 0.f) + xv.x;
    o.y = fmaxf(bf16_to_f32(mv.y) * sc + sh, 0.f) + xv.y;
    o.z = fmaxf(bf16_to_f32(mv.z) * sc + sh, 0.f) + xv.z;
    o.w = fmaxf(bf16_to_f32(mv.w) * sc + sh, 0.f) + xv.w;
    ((float4*)out)[i4] = o;
}

extern "C" void kernel_launch(void* const* d_in, const int* in_sizes, int n_in,
                              void* d_out, int out_size, void* d_ws, size_t ws_size,
                              hipStream_t stream) {
    const float* x      = (const float*)d_in[0];
    const float* w2     = (const float*)d_in[2];
    const float* gamma2 = (const float*)d_in[5];
    const float* beta2  = (const float*)d_in[6];
    const float* hs     = (const float*)d_in[7];
    const float* ss     = (const float*)d_in[8];
    float* out = (float*)d_out;

    char* ws = (char*)d_ws;
    unsigned short* xT  = (unsigned short*)(ws + OFF_XT);
    unsigned short* wfp = (unsigned short*)(ws + OFF_WF);
    int*            idp = (int*)(ws + OFF_IDX);
    unsigned short* mp  = (unsigned short*)(ws + OFF_M);
    float*          st  = (float*)(ws + OFF_STATS);
    float*          zp  = (float*)(ws + OFF_ZERO);

    k_prep<<<2481, 256, 0, stream>>>(x, xT, w2, hs, ss, wfp, idp, st, zp);
    k_conv<<<1024, 256, 0, stream>>>(xT, wfp, idp, ss, mp, st, (const unsigned short*)zp);
    k_apply<<<16384, 256, 0, stream>>>(mp, x, st, gamma2, beta2, out);
}

// Round 10
// 205.715 us; speedup vs baseline: 1.0193x; 1.0193x over previous
//
#include <hip/hip_runtime.h>
#include <stdint.h>

typedef __bf16 bf16x8 __attribute__((ext_vector_type(8)));
typedef float  f32x4  __attribute__((ext_vector_type(4)));

static constexpr int Bn = 32, Cn = 128, Hn = 64, Wn = 64, HWn = 4096;
static constexpr size_t OFF_XT    = 0;                       // 33,554,432 B (bf16 x, chunk-major NHWC)
static constexpr size_t OFF_WF    = 33554432;                // 221,184 B (B-fragment-ordered weights)
static constexpr size_t OFF_IDX   = 33775616;                // 1,536 B
static constexpr size_t OFF_M     = 33777152;                // 33,554,432 B (median result, bf16, NCHW)
static constexpr size_t OFF_STATS = 67331584;                // 32,768 B (32 shadow copies of [256] stats)
static constexpr size_t OFF_ZERO  = 67364352;                // 128 B zero page (halo OOB source)

__device__ __forceinline__ unsigned short f32_to_bf16(float f) {
    union { float f; unsigned u; } v; v.f = f;
    unsigned u = v.u;
    return (unsigned short)((u + 0x7FFFu + ((u >> 16) & 1u)) >> 16);
}
__device__ __forceinline__ float bf16_to_f32(unsigned short h) {
    union { unsigned u; float f; } v; v.u = ((unsigned)h) << 16;
    return v.f;
}
__device__ __forceinline__ float bf_lo(unsigned w) {
    union { unsigned u; float f; } v; v.u = w << 16; return v.f;
}
__device__ __forceinline__ float bf_hi(unsigned w) {
    union { unsigned u; float f; } v; v.u = w & 0xffff0000u; return v.f;
}
__device__ __forceinline__ float med3(float z0, float z1, float z2) {
    float lo = fminf(z0, z1), hi = fmaxf(z0, z1);
    return fmaxf(lo, fminf(hi, z2));
}
// direct global->LDS DMA, 16 B per lane (per-lane dest must equal wavebase + lane*16)
__device__ __forceinline__ void gload_lds16(const unsigned short* g, unsigned short* l) {
    __builtin_amdgcn_global_load_lds(
        (const __attribute__((address_space(1))) unsigned int*)(const void*)g,
        (__attribute__((address_space(3))) unsigned int*)(void*)l,
        16, 0, 0);
}

// ---- K_prep: wsk (blocks 0..431) + idx/zero (432) + transpose (433..2480) ----
__global__ __launch_bounds__(256) void k_prep(const float* __restrict__ x,
                                              unsigned short* __restrict__ xT,
                                              const float* __restrict__ w2,
                                              const float* __restrict__ hs,
                                              const float* __restrict__ ss,
                                              unsigned short* __restrict__ wf,
                                              int* __restrict__ idx,
                                              float* __restrict__ stats32,
                                              float* __restrict__ zerop) {
    __shared__ __align__(16) unsigned char smraw[20480];
    int t = threadIdx.x;
    if (blockIdx.x < 432) {
        // sketched weights: per-block LDS idx table, then LDS-scan + sparse w2 gather.
        int*   idxs = (int*)smraw;
        float* sss  = (float*)(smraw + 1536);
        for (int i = t; i < 384; i += 256) {
            int j = i >> 7, c = i & 127;
            int found = 0;
#pragma unroll
            for (int d = 0; d < 32; ++d)
                if (hs[(j * 32 + d) * 128 + c] > 0.5f) found = d;
            idxs[i] = found;
            sss[i]  = ss[i];
        }
        __syncthreads();
        int f = blockIdx.x * 256 + t;   // 110592 total
        int jj   = f & 7;
        int lane = (f >> 3) & 63;
        int nt   = (f >> 9) % 6;
        int qt   = f / (512 * 6);
        int tp   = qt % 9;
        int q    = qt / 9;
        int k  = ((lane >> 4) << 3) + jj;
        int ci = q * 32 + k;
        int n  = nt * 16 + (lane & 15);
        int j = n >> 5, d = n & 31;
        const int*   ij = idxs + j * 128;
        const float* sj = sss  + j * 128;
        float sum = 0.f;
        for (int c = 0; c < 128; ++c)
            if (ij[c] == d) sum += sj[c] * w2[(c * 128 + ci) * 9 + tp];
        wf[f] = f32_to_bf16(sum);
    } else if (blockIdx.x == 432) {
        // recover idx from one-hot hs + zero shadow stats + zero page
        for (int i = t; i < 384; i += 256) {
            int j = i >> 7, c = i & 127;
            int found = 0;
            for (int d = 0; d < 32; ++d)
                if (hs[(j * 32 + d) * 128 + c] > 0.5f) found = d;
            idx[i] = found;
        }
        for (int i = t; i < 8192; i += 256) stats32[i] = 0.f;
        if (t < 32) zerop[t] = 0.f;
    } else {
        // x NCHW fp32 -> xT[b][q][y][x][32ci] bf16 (chunk-major NHWC)
        unsigned short* sm = (unsigned short*)smraw;   // 256*40 ushorts = 20480 B
        int blk = blockIdx.x - 433;           // b*64 + q*16 + pt
        int pt = blk & 15, q = (blk >> 4) & 3, b = blk >> 6;
        int p0 = pt * 256;
        const float* xp = x + ((size_t)(b * Cn + q * 32) * HWn) + p0 + t;
#pragma unroll
        for (int cil = 0; cil < 32; ++cil)
            sm[t * 40 + cil] = f32_to_bf16(xp[(size_t)cil * HWn]);
        __syncthreads();
        uint4* dst = (uint4*)(xT + ((size_t)(b * 4 + q) * HWn + p0) * 32);
#pragma unroll
        for (int pass = 0; pass < 4; ++pass) {
            int pix = pass * 64 + (t >> 2);
            int ch  = t & 3;
            dst[pix * 4 + ch] = *(const uint4*)(&sm[pix * 40 + ch * 8]);
        }
    }
}

// ---- K2: conv(96ch) + unsketch + median3 + fused BN stats -> m (bf16, NCHW) ----
// grid 1024 = b*32 + tile; tile = 2 rows x 64 cols (128 px).
// 4 waves: wv = (row_l<<1)|nh -> wave owns output row row_l, N-half nh; acc[4][3]
// (48 AGPR). launch_bounds(256,3): total regs <=170 -> 3 blocks/CU = 12 waves/CU
// (was 8): the R5-R8 plateau at 44 us tracked the 2-waves/SIMD timeline, so +50%
// TLP is the lever. DMA staging needs no prefetch VGPRs (the R1 spill trap).
// Staging/swizzle is R5's MEASURED-good pair verbatim (64-B records,
// src cl=(k&3)^((r>>1)&3), read byo^=((byo>>7)&3)<<4 -> 0.67 conflicts/read;
// R8's invented 256-B variant was 7x worse). Double-buffered halo, one barrier/q.
__global__ __launch_bounds__(256, 3) void k_conv(const unsigned short* __restrict__ xT,
                                                 const unsigned short* __restrict__ wf,
                                                 const int* __restrict__ idx,
                                                 const float* __restrict__ ss,
                                                 unsigned short* __restrict__ m_out,
                                                 float* __restrict__ stats32,
                                                 const unsigned short* __restrict__ zerop) {
    // dbuf halo: 2 x 264 records x 64 B = 33,792 B; y [96][136] = 26,112 B aliases it
    __shared__ __align__(16) unsigned short sm[16896];
    int tid  = threadIdx.x;
    int blk  = blockIdx.x;
    int tile = blk & 31, b = blk >> 5;
    int ty0  = tile * 2;
    int wv   = tid >> 6, lane = tid & 63;
    int quad = lane >> 4, l15 = lane & 15;
    int row_l = wv >> 1, nh = wv & 1;

    // per-thread staging source offsets (ushort units), -1 = OOB/inactive.
    // 264 records x 4 chunks = 1056 chunks: 4 full rounds + 32-thread tail.
    int goff[5];
#pragma unroll
    for (int i = 0; i < 5; ++i) {
        int k = (i < 4) ? (tid + i * 256) : (tid + 1024);
        bool act = (i < 4) || (tid < 32);
        int r  = k >> 2;
        int cl = (k & 3) ^ ((r >> 1) & 3);          // inverse read-swizzle on source
        int hy = r / 66, hx = r - hy * 66;
        int gy = ty0 + hy - 1, gx = hx - 1;
        goff[i] = (act && gy >= 0 && gy < 64 && gx >= 0 && gx < 64)
                ? ((gy * 64 + gx) * 32 + cl * 8) : -1;
    }

    f32x4 acc[4][3];
#pragma unroll
    for (int a = 0; a < 4; ++a)
#pragma unroll
        for (int nb = 0; nb < 3; ++nb) acc[a][nb] = (f32x4){0.f, 0.f, 0.f, 0.f};

    const unsigned short* wl = wf + (size_t)(nh * 3) * 512 + lane * 8;

#define STAGE(qv, half)                                                               \
    {                                                                                 \
        const unsigned short* xq = xT + (size_t)(b * 4 + (qv)) * (HWn * 32);          \
        unsigned short* dstb = sm + (half) * 8448;                                    \
        _Pragma("unroll")                                                             \
        for (int i = 0; i < 4; ++i) {                                                 \
            int k = tid + i * 256;                                                    \
            gload_lds16((goff[i] >= 0) ? (xq + goff[i]) : zerop, dstb + k * 8);       \
        }                                                                             \
        if (tid < 32) {                                                               \
            int k = tid + 1024;                                                       \
            gload_lds16((goff[4] >= 0) ? (xq + goff[4]) : zerop, dstb + k * 8);       \
        }                                                                             \
    }

    STAGE(0, 0)
    __syncthreads();   // compiler drains vmcnt before barrier -> half 0 ready

    for (int q = 0; q < 4; ++q) {
        const unsigned char* cur = (const unsigned char*)(sm + (q & 1) * 8448);
        if (q < 3) STAGE(q + 1, (q + 1) & 1)   // DMA into other half; hides under taps
#pragma unroll
        for (int tp = 0; tp < 9; ++tp) {
            int dy = tp / 3, dx = tp % 3;
            bf16x8 bfr[3];
            const unsigned short* wb = wl + (size_t)((q * 9 + tp) * 6) * 512;
#pragma unroll
            for (int nb = 0; nb < 3; ++nb)
                bfr[nb] = *(const bf16x8*)(wb + nb * 512);
            bf16x8 afr[4];
#pragma unroll
            for (int mq = 0; mq < 4; ++mq) {
                int pix = (row_l + dy) * 66 + mq * 16 + l15 + dx;
                int byo = (pix << 6) + (quad << 4);
                byo ^= ((byo >> 7) & 3) << 4;        // read-side swizzle (matches source)
                afr[mq] = *(const bf16x8*)(cur + byo);
            }
            __builtin_amdgcn_s_setprio(1);
#pragma unroll
            for (int mq = 0; mq < 4; ++mq)
#pragma unroll
                for (int nb = 0; nb < 3; ++nb)
                    acc[mq][nb] = __builtin_amdgcn_mfma_f32_16x16x32_bf16(afr[mq], bfr[nb], acc[mq][nb], 0, 0, 0);
            __builtin_amdgcn_s_setprio(0);
        }
        __syncthreads();   // all waves done with cur; q+1 DMAs drained
    }
#undef STAGE

    // y-dump: channel-major [96][136] so the median gather vectorizes over pixels
#pragma unroll
    for (int mq = 0; mq < 4; ++mq)
#pragma unroll
        for (int nb = 0; nb < 3; ++nb) {
            int ch = nh * 48 + nb * 16 + l15;
            int px = row_l * 64 + mq * 16 + quad * 4;
            ushort4 v;
            v.x = f32_to_bf16(acc[mq][nb][0]);
            v.y = f32_to_bf16(acc[mq][nb][1]);
            v.z = f32_to_bf16(acc[mq][nb][2]);
            v.w = f32_to_bf16(acc[mq][nb][3]);
            *(ushort4*)(&sm[ch * 136 + px]) = v;
        }
    __syncthreads();
    // median-of-3: 16 lanes per channel (8 px per b128 read), 4 channels/wave/iter
    unsigned short* mpb = m_out + (size_t)b * Cn * HWn + tile * 128 + l15 * 8;
    float* stp = stats32 + (blk & 31) * 256;
#pragma unroll 2
    for (int i = 0; i < 8; ++i) {
        int c = wv * 32 + i * 4 + quad;
        int r0 = idx[c], r1 = 32 + idx[128 + c], r2 = 64 + idx[256 + c];
        float sg0 = ss[c], sg1 = ss[128 + c], sg2 = ss[256 + c];
        uint4 w0 = *(const uint4*)(&sm[r0 * 136 + l15 * 8]);
        uint4 w1 = *(const uint4*)(&sm[r1 * 136 + l15 * 8]);
        uint4 w2v = *(const uint4*)(&sm[r2 * 136 + l15 * 8]);
        const unsigned* u0 = (const unsigned*)&w0;
        const unsigned* u1 = (const unsigned*)&w1;
        const unsigned* u2 = (const unsigned*)&w2v;
        uint4 R;
        unsigned* rw = (unsigned*)&R;
        float s = 0.f, s2 = 0.f;
#pragma unroll
        for (int e = 0; e < 4; ++e) {
            float mlo = med3(sg0 * bf_lo(u0[e]), sg1 * bf_lo(u1[e]), sg2 * bf_lo(u2[e]));
            float mhi = med3(sg0 * bf_hi(u0[e]), sg1 * bf_hi(u1[e]), sg2 * bf_hi(u2[e]));
            s  += mlo + mhi;
            s2 += mlo * mlo + mhi * mhi;
            rw[e] = (unsigned)f32_to_bf16(mlo) | ((unsigned)f32_to_bf16(mhi) << 16);
        }
        *(uint4*)(mpb + (size_t)c * HWn) = R;
#pragma unroll
        for (int o = 8; o > 0; o >>= 1) { s += __shfl_xor(s, o); s2 += __shfl_xor(s2, o); }
        if (l15 == 0) { atomicAdd(&stp[c], s); atomicAdd(&stp[128 + c], s2); }
    }
}

// ---- K3: out = relu(m*sc+sh) + x; BN coefficients reduced once per block ----
__global__ __launch_bounds__(256) void k_apply(const unsigned short* __restrict__ m,
                                               const float* __restrict__ x,
                                               const float* __restrict__ stats32,
                                               const float* __restrict__ gamma,
                                               const float* __restrict__ beta,
                                               float* __restrict__ out) {
    __shared__ float co[2];
    int tid = threadIdx.x;
    int i4 = blockIdx.x * 256 + tid;              // 4,194,304 groups of 4
    int c = (blockIdx.x >> 2) & 127;              // block-uniform channel
    if (tid < 64) {
        float v = stats32[(tid & 31) * 256 + ((tid >> 5) << 7) + c];
#pragma unroll
        for (int o = 16; o > 0; o >>= 1) v += __shfl_xor(v, o);
        if ((tid & 31) == 0) co[tid >> 5] = v;
    }
    __syncthreads();
    const float N = 131072.f;
    float mean = co[0] / N;
    float var  = co[1] / N - mean * mean;
    float sc   = gamma[c] * rsqrtf(var + 1e-5f);
    float sh   = beta[c] - mean * sc;
    ushort4 mv = ((const ushort4*)m)[i4];
    float4  xv = ((const float4*)x)[i4];
    float4 o;
    o.x = fmaxf(bf16_to_f32(mv.x) * sc + sh, 0.f) + xv.x;
    o.y = fmaxf(bf16_to_f32(mv.y) * sc + sh, 0.f) + xv.y;
    o.z = fmaxf(bf16_to_f32(mv.z) * sc + sh, 0.f) + xv.z;
    o.w = fmaxf(bf16_to_f32(mv.w) * sc + sh, 0.f) + xv.w;
    ((float4*)out)[i4] = o;
}

extern "C" void kernel_launch(void* const* d_in, const int* in_sizes, int n_in,
                              void* d_out, int out_size, void* d_ws, size_t ws_size,
                              hipStream_t stream) {
    const float* x      = (const float*)d_in[0];
    const float* w2     = (const float*)d_in[2];
    const float* gamma2 = (const float*)d_in[5];
    const float* beta2  = (const float*)d_in[6];
    const float* hs     = (const float*)d_in[7];
    const float* ss     = (const float*)d_in[8];
    float* out = (float*)d_out;

    char* ws = (char*)d_ws;
    unsigned short* xT  = (unsigned short*)(ws + OFF_XT);
    unsigned short* wfp = (unsigned short*)(ws + OFF_WF);
    int*            idp = (int*)(ws + OFF_IDX);
    unsigned short* mp  = (unsigned short*)(ws + OFF_M);
    float*          st  = (float*)(ws + OFF_STATS);
    float*          zp  = (float*)(ws + OFF_ZERO);

    k_prep<<<2481, 256, 0, stream>>>(x, xT, w2, hs, ss, wfp, idp, st, zp);
    k_conv<<<1024, 256, 0, stream>>>(xT, wfp, idp, ss, mp, st, (const unsigned short*)zp);
    k_apply<<<16384, 256, 0, stream>>>(mp, x, st, gamma2, beta2, out);
}

// Round 13
// 193.102 us; speedup vs baseline: 1.0858x; 1.0653x over previous
//
#include <hip/hip_runtime.h>
#include <stdint.h>

typedef __bf16 bf16x8 __attribute__((ext_vector_type(8)));
typedef float  f32x4  __attribute__((ext_vector_type(4)));

static constexpr int Bn = 32, Cn = 128, Hn = 64, Wn = 64, HWn = 4096;
static constexpr size_t OFF_XT    = 0;                       // 33,554,432 B (bf16 x, chunk-major NHWC)
static constexpr size_t OFF_WF    = 33554432;                // 221,184 B (B-fragment-ordered weights)
static constexpr size_t OFF_IDX   = 33775616;                // 1,536 B
static constexpr size_t OFF_M     = 33777152;                // 33,554,432 B (median result, bf16, NCHW)
static constexpr size_t OFF_STATS = 67331584;                // 16,384 B (16 shadow copies of [256] stats)
static constexpr size_t OFF_ZERO  = 67347968;                // 128 B zero page (halo OOB source)

__device__ __forceinline__ unsigned short f32_to_bf16(float f) {
    union { float f; unsigned u; } v; v.f = f;
    unsigned u = v.u;
    return (unsigned short)((u + 0x7FFFu + ((u >> 16) & 1u)) >> 16);
}
__device__ __forceinline__ float bf16_to_f32(unsigned short h) {
    union { unsigned u; float f; } v; v.u = ((unsigned)h) << 16;
    return v.f;
}
__device__ __forceinline__ float bf_lo(unsigned w) {
    union { unsigned u; float f; } v; v.u = w << 16; return v.f;
}
__device__ __forceinline__ float bf_hi(unsigned w) {
    union { unsigned u; float f; } v; v.u = w & 0xffff0000u; return v.f;
}
__device__ __forceinline__ float med3(float z0, float z1, float z2) {
    float lo = fminf(z0, z1), hi = fmaxf(z0, z1);
    return fmaxf(lo, fminf(hi, z2));
}
// direct global->LDS DMA, 16 B per lane (per-lane dest must equal wavebase + lane*16)
__device__ __forceinline__ void gload_lds16(const unsigned short* g, unsigned short* l) {
    __builtin_amdgcn_global_load_lds(
        (const __attribute__((address_space(1))) unsigned int*)(const void*)g,
        (__attribute__((address_space(3))) unsigned int*)(void*)l,
        16, 0, 0);
}

// ---- K_prep: wsk (blocks 0..431, runs FIRST) + idx/zero (432) + transpose (433..2480) ----
__global__ __launch_bounds__(256) void k_prep(const float* __restrict__ x,
                                              unsigned short* __restrict__ xT,
                                              const float* __restrict__ w2,
                                              const float* __restrict__ hs,
                                              const float* __restrict__ ss,
                                              unsigned short* __restrict__ wf,
                                              int* __restrict__ idx,
                                              float* __restrict__ stats16,
                                              float* __restrict__ zerop) {
    __shared__ __align__(16) unsigned char smraw[20480];
    int t = threadIdx.x;
    if (blockIdx.x < 432) {
        // sketched weights: per-block LDS idx table, then LDS-scan + sparse w2 gather.
        int*   idxs = (int*)smraw;
        float* sss  = (float*)(smraw + 1536);
        for (int i = t; i < 384; i += 256) {
            int j = i >> 7, c = i & 127;
            int found = 0;
#pragma unroll
            for (int d = 0; d < 32; ++d)
                if (hs[(j * 32 + d) * 128 + c] > 0.5f) found = d;
            idxs[i] = found;
            sss[i]  = ss[i];
        }
        __syncthreads();
        int f = blockIdx.x * 256 + t;   // 110592 total
        int jj   = f & 7;
        int lane = (f >> 3) & 63;
        int nt   = (f >> 9) % 6;
        int qt   = f / (512 * 6);
        int tp   = qt % 9;
        int q    = qt / 9;
        int k  = ((lane >> 4) << 3) + jj;
        int ci = q * 32 + k;
        int n  = nt * 16 + (lane & 15);
        int j = n >> 5, d = n & 31;
        const int*   ij = idxs + j * 128;
        const float* sj = sss  + j * 128;
        float sum = 0.f;
        for (int c = 0; c < 128; ++c)
            if (ij[c] == d) sum += sj[c] * w2[(c * 128 + ci) * 9 + tp];
        wf[f] = f32_to_bf16(sum);
    } else if (blockIdx.x == 432) {
        // recover idx from one-hot hs + zero shadow stats + zero page
        for (int i = t; i < 384; i += 256) {
            int j = i >> 7, c = i & 127;
            int found = 0;
            for (int d = 0; d < 32; ++d)
                if (hs[(j * 32 + d) * 128 + c] > 0.5f) found = d;
            idx[i] = found;
        }
        for (int i = t; i < 4096; i += 256) stats16[i] = 0.f;
        if (t < 32) zerop[t] = 0.f;
    } else {
        // x NCHW fp32 -> xT[b][q][y][x][32ci] bf16 (chunk-major NHWC).
        // Vectorized (G13): float4 loads (16 B/lane, 8 passes) into channel-major
        // LDS [32][266]; output record layout is BIT-IDENTICAL to the validated
        // scalar transpose (chunk ch of pixel pix holds channels ch*8..ch*8+7).
        unsigned short* sm2 = (unsigned short*)smraw;   // 32*266 = 8512 ushorts
        int blk = blockIdx.x - 433;           // b*64 + q*16 + pt
        int pt = blk & 15, q = (blk >> 4) & 3, b = blk >> 6;
        int p0 = pt * 256;
        int l = t & 63, cg = t >> 6;
#pragma unroll
        for (int pp = 0; pp < 8; ++pp) {
            int cil = pp * 4 + cg;
            float4 v = *(const float4*)(x + ((size_t)(b * Cn + q * 32 + cil) * HWn) + p0 + l * 4);
            ushort2 w01, w23;
            w01.x = f32_to_bf16(v.x); w01.y = f32_to_bf16(v.y);
            w23.x = f32_to_bf16(v.z); w23.y = f32_to_bf16(v.w);
            *(ushort2*)(&sm2[cil * 266 + l * 4])     = w01;
            *(ushort2*)(&sm2[cil * 266 + l * 4 + 2]) = w23;
        }
        __syncthreads();
        uint4* dst = (uint4*)(xT + ((size_t)(b * 4 + q) * HWn + p0) * 32);
#pragma unroll
        for (int pass = 0; pass < 4; ++pass) {
            int pix = pass * 64 + (t >> 2);
            int c0  = (t & 3) * 8;
            uint4 R;
            unsigned* rw = (unsigned*)&R;
#pragma unroll
            for (int e = 0; e < 4; ++e) {
                unsigned lo = sm2[(c0 + 2 * e)     * 266 + pix];
                unsigned hi = sm2[(c0 + 2 * e + 1) * 266 + pix];
                rw[e] = lo | (hi << 16);
            }
            dst[pix * 4 + (t & 3)] = R;
        }
    }
}

// ---- K2: conv(96ch) + unsketch + median3 + fused BN stats -> m (bf16, NCHW) ----
// VALIDATED 44.3 us config (passed full harness 5x): grid 512 = b*16 + tile;
// tile = 4 rows x 64 cols; DMA double-buffered halo staging, global L2-hot bfr,
// rule-#21 swizzle pair, channel-major y epilogue, 16-shadow stats.
__global__ __launch_bounds__(256, 2) void k_conv(const unsigned short* __restrict__ xT,
                                                 const unsigned short* __restrict__ wf,
                                                 const int* __restrict__ idx,
                                                 const float* __restrict__ ss,
                                                 unsigned short* __restrict__ m_out,
                                                 float* __restrict__ stats16,
                                                 const unsigned short* __restrict__ zerop) {
    // two staging halves of 396*32 = 12672 ushorts each, aliased with y [96][264] = 25344
    __shared__ __align__(16) unsigned short sm[25344];
    __shared__ int   idx_sh[384];
    __shared__ float ss_sh[384];
    int tid  = threadIdx.x;
    int blk  = blockIdx.x;
    int tile = blk & 15, b = blk >> 4;
    int ty0  = tile * 4;
    int wv   = tid >> 6, lane = tid & 63;
    int quad = lane >> 4, l15 = lane & 15;

    for (int i = tid; i < 384; i += 256) { idx_sh[i] = idx[i]; ss_sh[i] = ss[i]; }

    // per-thread staging source offsets (ushort units from xq base), -1 = OOB/inactive
    int goff[7];
#pragma unroll
    for (int i = 0; i < 7; ++i) {
        int k = (i < 6) ? (tid + i * 256) : (tid + 1536);
        bool act = (i < 6) || (tid < 48);
        int r  = k >> 2;
        int cl = (k & 3) ^ ((r >> 1) & 3);          // inverse read-swizzle on the source
        int hy = r / 66, hx = r - hy * 66;
        int gy = ty0 + hy - 1, gx = hx - 1;
        goff[i] = (act && gy >= 0 && gy < 64 && gx >= 0 && gx < 64)
                ? ((gy * 64 + gx) * 32 + cl * 8) : -1;
    }

    f32x4 acc[4][6];
#pragma unroll
    for (int a = 0; a < 4; ++a)
#pragma unroll
        for (int nb = 0; nb < 6; ++nb) acc[a][nb] = (f32x4){0.f, 0.f, 0.f, 0.f};

    const unsigned short* wl = wf + lane * 8;

    // prologue: stage q=0 into half 0
    {
        const unsigned short* xq = xT + (size_t)(b * 4) * (HWn * 32);
#pragma unroll
        for (int i = 0; i < 6; ++i) {
            int k = tid + i * 256;
            gload_lds16((goff[i] >= 0) ? (xq + goff[i]) : zerop, &sm[k * 8]);
        }
        if (tid < 48) {
            int k = tid + 1536;
            gload_lds16((goff[6] >= 0) ? (xq + goff[6]) : zerop, &sm[k * 8]);
        }
    }
    __syncthreads();   // drains vmcnt before barrier -> half 0 ready

    for (int q = 0; q < 4; ++q) {
        unsigned short* cur = sm + (q & 1) * 12672;
        if (q < 3) {   // issue q+1 staging into the other half; latency hides under MFMAs
            const unsigned short* xq = xT + (size_t)(b * 4 + q + 1) * (HWn * 32);
            unsigned short* nxt = sm + ((q + 1) & 1) * 12672;
#pragma unroll
            for (int i = 0; i < 6; ++i) {
                int k = tid + i * 256;
                gload_lds16((goff[i] >= 0) ? (xq + goff[i]) : zerop, &nxt[k * 8]);
            }
            if (tid < 48) {
                int k = tid + 1536;
                gload_lds16((goff[6] >= 0) ? (xq + goff[6]) : zerop, &nxt[k * 8]);
            }
        }
#pragma unroll
        for (int tp = 0; tp < 9; ++tp) {
            int dy = tp / 3, dx = tp % 3;
            bf16x8 bfr[6];
            const unsigned short* wb = wl + (size_t)((q * 9 + tp) * 6) * 512;
#pragma unroll
            for (int nb = 0; nb < 6; ++nb)
                bfr[nb] = *(const bf16x8*)(wb + nb * 512);
            bf16x8 afr[4];
#pragma unroll
            for (int mq = 0; mq < 4; ++mq) {
                int pix = (wv + dy) * 66 + mq * 16 + l15 + dx;
                int byo = (pix << 6) + (quad << 4);
                byo ^= ((byo >> 7) & 3) << 4;        // read-side swizzle (matches source)
                afr[mq] = *(const bf16x8*)((const unsigned char*)cur + byo);
            }
#pragma unroll
            for (int mq = 0; mq < 4; ++mq)
#pragma unroll
                for (int nb = 0; nb < 6; ++nb)
                    acc[mq][nb] = __builtin_amdgcn_mfma_f32_16x16x32_bf16(afr[mq], bfr[nb], acc[mq][nb], 0, 0, 0);
        }
        __syncthreads();   // drains q+1 staging DMAs; next q reads the other half
    }

    // y-dump: channel-major [ch][264] so the median gather vectorizes over pixels
#pragma unroll
    for (int mq = 0; mq < 4; ++mq)
#pragma unroll
        for (int nb = 0; nb < 6; ++nb) {
            int ch = nb * 16 + l15;
            int px = wv * 64 + mq * 16 + quad * 4;
            ushort4 v;
            v.x = f32_to_bf16(acc[mq][nb][0]);
            v.y = f32_to_bf16(acc[mq][nb][1]);
            v.z = f32_to_bf16(acc[mq][nb][2]);
            v.w = f32_to_bf16(acc[mq][nb][3]);
            *(ushort4*)(&sm[ch * 264 + px]) = v;
        }
    __syncthreads();
    // median-of-3 (8 px per b128 read) + coalesced store + shadowed per-channel stats
    int half = lane >> 5, p8 = lane & 31;
    unsigned short* mpb = m_out + (size_t)b * Cn * HWn + tile * 256 + p8 * 8;
    float* stp = stats16 + (blk & 15) * 256;
#pragma unroll 2
    for (int i = 0; i < 16; ++i) {
        int c = wv * 32 + i * 2 + half;        // 32 lanes share one channel
        int r0 = idx_sh[c], r1 = 32 + idx_sh[128 + c], r2 = 64 + idx_sh[256 + c];
        float sg0 = ss_sh[c], sg1 = ss_sh[128 + c], sg2 = ss_sh[256 + c];
        uint4 w0 = *(const uint4*)(&sm[r0 * 264 + p8 * 8]);
        uint4 w1 = *(const uint4*)(&sm[r1 * 264 + p8 * 8]);
        uint4 w2v = *(const uint4*)(&sm[r2 * 264 + p8 * 8]);
        const unsigned* u0 = (const unsigned*)&w0;
        const unsigned* u1 = (const unsigned*)&w1;
        const unsigned* u2 = (const unsigned*)&w2v;
        uint4 R;
        unsigned* rw = (unsigned*)&R;
        float s = 0.f, s2 = 0.f;
#pragma unroll
        for (int e = 0; e < 4; ++e) {
            float mlo = med3(sg0 * bf_lo(u0[e]), sg1 * bf_lo(u1[e]), sg2 * bf_lo(u2[e]));
            float mhi = med3(sg0 * bf_hi(u0[e]), sg1 * bf_hi(u1[e]), sg2 * bf_hi(u2[e]));
            s  += mlo + mhi;
            s2 += mlo * mlo + mhi * mhi;
            rw[e] = (unsigned)f32_to_bf16(mlo) | ((unsigned)f32_to_bf16(mhi) << 16);
        }
        *(uint4*)(mpb + (size_t)c * HWn) = R;
#pragma unroll
        for (int o = 16; o > 0; o >>= 1) { s += __shfl_xor(s, o); s2 += __shfl_xor(s2, o); }
        if ((lane & 31) == 0) { atomicAdd(&stp[c], s); atomicAdd(&stp[128 + c], s2); }
    }
}

// ---- K3: out = relu(m*sc+sh) + x; BN coefficients reduced once per block (LDS) ----
// VALIDATED config (passed full harness 5x): 16384 blocks, co[2] reduction.
__global__ __launch_bounds__(256) void k_apply(const unsigned short* __restrict__ m,
                                               const float* __restrict__ x,
                                               const float* __restrict__ stats16,
                                               const float* __restrict__ gamma,
                                               const float* __restrict__ beta,
                                               float* __restrict__ out) {
    __shared__ float co[2];
    int tid = threadIdx.x;
    int i4 = blockIdx.x * 256 + tid;              // 4,194,304 groups of 4
    int c = (blockIdx.x >> 2) & 127;              // block-uniform channel
    if (tid < 32) {
        float v = stats16[(tid & 15) * 256 + ((tid >> 4) << 7) + c];
#pragma unroll
        for (int o = 8; o > 0; o >>= 1) v += __shfl_xor(v, o);
        if ((tid & 15) == 0) co[tid >> 4] = v;
    }
    __syncthreads();
    const float N = 131072.f;
    float mean = co[0] / N;
    float var  = co[1] / N - mean * mean;
    float sc   = gamma[c] * rsqrtf(var + 1e-5f);
    float sh   = beta[c] - mean * sc;
    ushort4 mv = ((const ushort4*)m)[i4];
    float4  xv = ((const float4*)x)[i4];
    float4 o;
    o.x = fmaxf(bf16_to_f32(mv.x) * sc + sh, 0.f) + xv.x;
    o.y = fmaxf(bf16_to_f32(mv.y) * sc + sh, 0.f) + xv.y;
    o.z = fmaxf(bf16_to_f32(mv.z) * sc + sh, 0.f) + xv.z;
    o.w = fmaxf(bf16_to_f32(mv.w) * sc + sh, 0.f) + xv.w;
    ((float4*)out)[i4] = o;
}

extern "C" void kernel_launch(void* const* d_in, const int* in_sizes, int n_in,
                              void* d_out, int out_size, void* d_ws, size_t ws_size,
                              hipStream_t stream) {
    const float* x      = (const float*)d_in[0];
    const float* w2     = (const float*)d_in[2];
    const float* gamma2 = (const float*)d_in[5];
    const float* beta2  = (const float*)d_in[6];
    const float* hs     = (const float*)d_in[7];
    const float* ss     = (const float*)d_in[8];
    float* out = (float*)d_out;

    char* ws = (char*)d_ws;
    unsigned short* xT  = (unsigned short*)(ws + OFF_XT);
    unsigned short* wfp = (unsigned short*)(ws + OFF_WF);
    int*            idp = (int*)(ws + OFF_IDX);
    unsigned short* mp  = (unsigned short*)(ws + OFF_M);
    float*          st  = (float*)(ws + OFF_STATS);
    float*          zp  = (float*)(ws + OFF_ZERO);

    k_prep<<<2481, 256, 0, stream>>>(x, xT, w2, hs, ss, wfp, idp, st, zp);
    k_conv<<<512, 256, 0, stream>>>(xT, wfp, idp, ss, mp, st, (const unsigned short*)zp);
    k_apply<<<16384, 256, 0, stream>>>(mp, x, st, gamma2, beta2, out);
}